// Round 1
// baseline (352.268 us; speedup 1.0000x reference)
//
#include <hip/hip_runtime.h>

typedef unsigned short u16;
typedef unsigned int u32;
typedef __attribute__((ext_vector_type(8))) __bf16 bf16x8;
typedef __attribute__((ext_vector_type(4))) float floatx4;

#define DEV __device__ __forceinline__

DEV u16 f2bf(float f) {
  u32 u = __builtin_bit_cast(u32, f);
  u = (u + 0x7fffu + ((u >> 16) & 1u)) >> 16;
  return (u16)u;
}
DEV float bf2f(u16 h) {
  u32 u = ((u32)h) << 16;
  return __builtin_bit_cast(float, u);
}

// ---------------- convert: x -> bf16, weights -> bf16 transposed -------------
// xb:    [4096][256]  bf16  (copy of x)
// WcatT: [2048][256]  bf16  (cols: 0..511 Wq | 512..1023 Wk | 1024..1535 Wv | 1536..2047 Wg), n-major
// WoT:   [256][512]   bf16  (WoT[n][k] = Wo[k][n])
__global__ void convert_k(const float* __restrict__ x, const float* __restrict__ Wq,
                          const float* __restrict__ Wkv, const float* __restrict__ Wg,
                          const float* __restrict__ Wo,
                          u16* __restrict__ xb, u16* __restrict__ WcatT, u16* __restrict__ WoT) {
  int i = blockIdx.x * 256 + threadIdx.x;
  if (i < 1048576) { xb[i] = f2bf(x[i]); return; }
  i -= 1048576;
  if (i < 524288) {
    int n = i >> 8, kk = i & 255;
    float v;
    if (n < 512) v = Wq[kk * 512 + n];
    else if (n < 1536) v = Wkv[kk * 1024 + (n - 512)];
    else v = Wg[kk * 512 + (n - 1536)];
    WcatT[i] = f2bf(v);
    return;
  }
  i -= 524288;
  if (i < 131072) {
    int n = i >> 9, kk = i & 511;
    WoT[i] = f2bf(Wo[kk * 256 + n]);
  }
}

// ---------------- GEMM1: [4096,256] x [256,2048] -> q,k,v,g ------------------
__global__ __launch_bounds__(256) void gemm_qkvg(
    const u16* __restrict__ xb, const u16* __restrict__ WcatT, const float* __restrict__ bg,
    u16* __restrict__ qb, u16* __restrict__ kb, u16* __restrict__ vb, u16* __restrict__ gb) {
  __shared__ __attribute__((aligned(16))) u16 As[128 * 40];
  __shared__ __attribute__((aligned(16))) u16 Bs[128 * 40];
  const int tid = threadIdx.x;
  const int wave = tid >> 6, lane = tid & 63;
  const int lane15 = lane & 15, quad = lane >> 4;
  const int rm0 = blockIdx.x * 128;
  const int cn0 = blockIdx.y * 128;
  const int wm = (wave & 1) * 64, wn = (wave >> 1) * 64;
  const int arow = tid >> 2;
  const int aseg = (tid & 3) * 8;
  floatx4 acc[4][4] = {};
#pragma unroll 1
  for (int k0 = 0; k0 < 256; k0 += 32) {
#pragma unroll
    for (int p = 0; p < 2; ++p) {
      int row = arow + p * 64;
      uint4 va = *(const uint4*)(xb + (rm0 + row) * 256 + k0 + aseg);
      *(uint4*)(As + row * 40 + aseg) = va;
      uint4 vbv = *(const uint4*)(WcatT + (cn0 + row) * 256 + k0 + aseg);
      *(uint4*)(Bs + row * 40 + aseg) = vbv;
    }
    __syncthreads();
    bf16x8 af[4], bfr[4];
#pragma unroll
    for (int mt = 0; mt < 4; ++mt) af[mt] = *(const bf16x8*)(As + (wm + mt * 16 + lane15) * 40 + quad * 8);
#pragma unroll
    for (int nt = 0; nt < 4; ++nt) bfr[nt] = *(const bf16x8*)(Bs + (wn + nt * 16 + lane15) * 40 + quad * 8);
#pragma unroll
    for (int mt = 0; mt < 4; ++mt)
#pragma unroll
      for (int nt = 0; nt < 4; ++nt)
        acc[mt][nt] = __builtin_amdgcn_mfma_f32_16x16x32_bf16(af[mt], bfr[nt], acc[mt][nt], 0, 0, 0);
    __syncthreads();
  }
  // epilogue: scatter to q/k/v/g layouts (whole block maps to one region)
#pragma unroll
  for (int mt = 0; mt < 4; ++mt)
#pragma unroll
    for (int nt = 0; nt < 4; ++nt)
#pragma unroll
      for (int r = 0; r < 4; ++r) {
        int row = rm0 + wm + mt * 16 + quad * 4 + r;
        int col = cn0 + wn + nt * 16 + lane15;
        float v = acc[mt][nt][r];
        int b = row >> 10, n = row & 1023;
        if (col < 512) {
          int h = col >> 6, d = col & 63;
          qb[((b * 8 + h) * 1024 + n) * 64 + d] = f2bf(v * 0.125f);
        } else if (col < 1024) {
          int c = col - 512, h = c >> 6, d = c & 63;
          kb[((b * 8 + h) * 1024 + n) * 64 + d] = f2bf(v);
        } else if (col < 1536) {
          int c = col - 1024, h = c >> 6, d = c & 63;
          vb[((b * 8 + h) * 1024 + n) * 64 + d] = f2bf(v);
        } else {
          int c = col - 1536;
          float g = 1.0f / (1.0f + __expf(-(v + bg[c])));
          gb[row * 512 + c] = f2bf(g);
        }
      }
}

// ---------------- attention: flash-style, 64 Q-rows per block ----------------
__global__ __launch_bounds__(256) void attn_k(
    const u16* __restrict__ qb, const u16* __restrict__ kb, const u16* __restrict__ vb,
    const float* __restrict__ bias, const u16* __restrict__ gb, u16* __restrict__ outgb) {
  __shared__ __attribute__((aligned(16))) u16 Ks[128 * 72];
  __shared__ __attribute__((aligned(16))) u16 VT[64 * 136];
  __shared__ __attribute__((aligned(16))) u16 Ps[4 * 16 * 136];
  const int tid = threadIdx.x;
  const int wave = tid >> 6, lane = tid & 63;
  const int lane15 = lane & 15, quad = lane >> 4;
  const int bh = blockIdx.x;   // b*8+h
  const int q0 = blockIdx.y * 64;

  bf16x8 qf[2];
  {
    const u16* qrow = qb + (bh * 1024 + q0 + wave * 16 + lane15) * 64;
    qf[0] = *(const bf16x8*)(qrow + quad * 8);
    qf[1] = *(const bf16x8*)(qrow + 32 + quad * 8);
  }
  floatx4 oacc[4] = {};
  float m_run[4], l_run[4];
#pragma unroll
  for (int r = 0; r < 4; ++r) { m_run[r] = -1e38f; l_run[r] = 0.f; }
  u16* Pw = Ps + wave * 16 * 136;

#pragma unroll 1
  for (int kt = 0; kt < 8; ++kt) {
    const int kbase = kt * 128;
    __syncthreads();
    {  // stage K tile [128][64] -> Ks[128][72]
      int row = tid >> 1;
      int seg = (tid & 1) * 32;
      const uint4* s4 = (const uint4*)(kb + (bh * 1024 + kbase + row) * 64 + seg);
      uint4* dst = (uint4*)(Ks + row * 72 + seg);
      dst[0] = s4[0]; dst[1] = s4[1]; dst[2] = s4[2]; dst[3] = s4[3];
    }
    {  // stage V tile transposed: v[key][d] -> VT[d][136]+key
      int row = tid >> 1;
      int seg = (tid & 1) * 32;
      const uint4* s4 = (const uint4*)(vb + (bh * 1024 + kbase + row) * 64 + seg);
#pragma unroll
      for (int u = 0; u < 4; ++u) {
        uint4 pv = s4[u];
        u16 tmp[8];
        *(uint4*)tmp = pv;
#pragma unroll
        for (int e = 0; e < 8; ++e) VT[(seg + u * 8 + e) * 136 + row] = tmp[e];
      }
    }
    __syncthreads();

    // S = Q @ K^T  (16x16 tiles over 128 keys)
    floatx4 s[8];
#pragma unroll
    for (int nt = 0; nt < 8; ++nt) {
      bf16x8 kf0 = *(const bf16x8*)(Ks + (nt * 16 + lane15) * 72 + quad * 8);
      bf16x8 kf1 = *(const bf16x8*)(Ks + (nt * 16 + lane15) * 72 + 32 + quad * 8);
      floatx4 z = {};
      z = __builtin_amdgcn_mfma_f32_16x16x32_bf16(qf[0], kf0, z, 0, 0, 0);
      s[nt] = __builtin_amdgcn_mfma_f32_16x16x32_bf16(qf[1], kf1, z, 0, 0, 0);
    }
    // + bias (fp32, the dominant HBM stream)
    const float* bptr = bias + ((long)(bh * 1024 + q0 + wave * 16)) * 1024 + kbase;
#pragma unroll
    for (int nt = 0; nt < 8; ++nt)
#pragma unroll
      for (int r = 0; r < 4; ++r)
        s[nt][r] += bptr[(quad * 4 + r) * 1024 + nt * 16 + lane15];

    // online softmax (rows live in quads: row = quad*4+r, cols spread over 16 lanes)
#pragma unroll
    for (int r = 0; r < 4; ++r) {
      float mx = s[0][r];
#pragma unroll
      for (int nt = 1; nt < 8; ++nt) mx = fmaxf(mx, s[nt][r]);
#pragma unroll
      for (int off = 1; off < 16; off <<= 1) mx = fmaxf(mx, __shfl_xor(mx, off, 64));
      float m_new = fmaxf(m_run[r], mx);
      float alpha = __expf(m_run[r] - m_new);
      float ssum = 0.f;
#pragma unroll
      for (int nt = 0; nt < 8; ++nt) {
        float p = __expf(s[nt][r] - m_new);
        s[nt][r] = p;
        ssum += p;
      }
#pragma unroll
      for (int off = 1; off < 16; off <<= 1) ssum += __shfl_xor(ssum, off, 64);
      l_run[r] = l_run[r] * alpha + ssum;
      m_run[r] = m_new;
#pragma unroll
      for (int dt = 0; dt < 4; ++dt) oacc[dt][r] *= alpha;
    }
    // P -> LDS (C-layout write, A-layout read)
#pragma unroll
    for (int nt = 0; nt < 8; ++nt)
#pragma unroll
      for (int r = 0; r < 4; ++r)
        Pw[(quad * 4 + r) * 136 + nt * 16 + lane15] = f2bf(s[nt][r]);
    __syncthreads();
    // O += P @ V
    bf16x8 pf[4];
#pragma unroll
    for (int ck = 0; ck < 4; ++ck) pf[ck] = *(const bf16x8*)(Pw + lane15 * 136 + ck * 32 + quad * 8);
#pragma unroll
    for (int dt = 0; dt < 4; ++dt)
#pragma unroll
      for (int ck = 0; ck < 4; ++ck) {
        bf16x8 vf = *(const bf16x8*)(VT + (dt * 16 + lane15) * 136 + ck * 32 + quad * 8);
        oacc[dt] = __builtin_amdgcn_mfma_f32_16x16x32_bf16(pf[ck], vf, oacc[dt], 0, 0, 0);
      }
  }
  // epilogue: normalize, gate, store bf16 outg [4096][512]
  const int h = bh & 7, b = bh >> 3;
#pragma unroll
  for (int dt = 0; dt < 4; ++dt)
#pragma unroll
    for (int r = 0; r < 4; ++r) {
      int nrow = q0 + wave * 16 + quad * 4 + r;
      float v = oacc[dt][r] / l_run[r];
      int inner = h * 64 + dt * 16 + lane15;
      long idx = ((long)(b * 1024 + nrow)) * 512 + inner;
      float g = bf2f(gb[idx]);
      outgb[idx] = f2bf(v * g);
    }
}

// ---------------- GEMM2: [4096,512] x [512,256] + bo -> out fp32 -------------
__global__ __launch_bounds__(256) void gemm_out(
    const u16* __restrict__ og, const u16* __restrict__ WoT, const float* __restrict__ bo,
    float* __restrict__ out) {
  __shared__ __attribute__((aligned(16))) u16 As[128 * 40];
  __shared__ __attribute__((aligned(16))) u16 Bs[128 * 40];
  const int tid = threadIdx.x;
  const int wave = tid >> 6, lane = tid & 63;
  const int lane15 = lane & 15, quad = lane >> 4;
  const int rm0 = blockIdx.x * 128;
  const int cn0 = blockIdx.y * 128;
  const int wm = (wave & 1) * 64, wn = (wave >> 1) * 64;
  const int arow = tid >> 2;
  const int aseg = (tid & 3) * 8;
  floatx4 acc[4][4] = {};
#pragma unroll 1
  for (int k0 = 0; k0 < 512; k0 += 32) {
#pragma unroll
    for (int p = 0; p < 2; ++p) {
      int row = arow + p * 64;
      uint4 va = *(const uint4*)(og + (rm0 + row) * 512 + k0 + aseg);
      *(uint4*)(As + row * 40 + aseg) = va;
      uint4 vbv = *(const uint4*)(WoT + (cn0 + row) * 512 + k0 + aseg);
      *(uint4*)(Bs + row * 40 + aseg) = vbv;
    }
    __syncthreads();
    bf16x8 af[4], bfr[4];
#pragma unroll
    for (int mt = 0; mt < 4; ++mt) af[mt] = *(const bf16x8*)(As + (wm + mt * 16 + lane15) * 40 + quad * 8);
#pragma unroll
    for (int nt = 0; nt < 4; ++nt) bfr[nt] = *(const bf16x8*)(Bs + (wn + nt * 16 + lane15) * 40 + quad * 8);
#pragma unroll
    for (int mt = 0; mt < 4; ++mt)
#pragma unroll
      for (int nt = 0; nt < 4; ++nt)
        acc[mt][nt] = __builtin_amdgcn_mfma_f32_16x16x32_bf16(af[mt], bfr[nt], acc[mt][nt], 0, 0, 0);
    __syncthreads();
  }
#pragma unroll
  for (int mt = 0; mt < 4; ++mt)
#pragma unroll
    for (int nt = 0; nt < 4; ++nt)
#pragma unroll
      for (int r = 0; r < 4; ++r) {
        int row = rm0 + wm + mt * 16 + quad * 4 + r;
        int col = cn0 + wn + nt * 16 + lane15;
        out[row * 256 + col] = acc[mt][nt][r] + bo[col];
      }
}

extern "C" void kernel_launch(void* const* d_in, const int* in_sizes, int n_in,
                              void* d_out, int out_size, void* d_ws, size_t ws_size,
                              hipStream_t stream) {
  const float* x = (const float*)d_in[0];
  const float* bias = (const float*)d_in[1];
  const float* Wq = (const float*)d_in[2];
  const float* Wkv = (const float*)d_in[3];
  const float* Wo = (const float*)d_in[4];
  const float* bo = (const float*)d_in[5];
  const float* Wg = (const float*)d_in[6];
  const float* bg = (const float*)d_in[7];
  float* out = (float*)d_out;
  char* ws = (char*)d_ws;
  u16* xb    = (u16*)(ws);                 // 4096*256   bf16  (2 MB)
  u16* WcatT = (u16*)(ws + 2097152);       // 2048*256   bf16  (1 MB)
  u16* WoT   = (u16*)(ws + 3145728);       // 256*512    bf16  (256 KB)
  u16* qb    = (u16*)(ws + 3407872);       // 32*1024*64 bf16  (4 MB)
  u16* kb    = (u16*)(ws + 7602176);       // 4 MB
  u16* vb    = (u16*)(ws + 11796480);      // 4 MB
  u16* gb    = (u16*)(ws + 15990784);      // 4096*512   bf16  (4 MB)
  u16* ogb   = (u16*)(ws + 20185088);      // 4096*512   bf16  (4 MB)

  convert_k<<<6656, 256, 0, stream>>>(x, Wq, Wkv, Wg, Wo, xb, WcatT, WoT);
  dim3 g1(32, 16);
  gemm_qkvg<<<g1, 256, 0, stream>>>(xb, WcatT, bg, qb, kb, vb, gb);
  dim3 g2(32, 16);
  attn_k<<<g2, 256, 0, stream>>>(qb, kb, vb, bias, gb, ogb);
  dim3 g3(32, 2);
  gemm_out<<<g3, 256, 0, stream>>>(ogb, WoT, bo, out);
}

// Round 2
// 296.285 us; speedup vs baseline: 1.1889x; 1.1889x over previous
//
#include <hip/hip_runtime.h>

typedef unsigned short u16;
typedef unsigned int u32;
typedef __attribute__((ext_vector_type(8))) __bf16 bf16x8;
typedef __attribute__((ext_vector_type(4))) float floatx4;

#define DEV __device__ __forceinline__

DEV u16 f2bf(float f) {
  u32 u = __builtin_bit_cast(u32, f);
  u = (u + 0x7fffu + ((u >> 16) & 1u)) >> 16;
  return (u16)u;
}
DEV float bf2f(u16 h) {
  u32 u = ((u32)h) << 16;
  return __builtin_bit_cast(float, u);
}
DEV floatx4 MFMA(bf16x8 a, bf16x8 b, floatx4 c) {
  return __builtin_amdgcn_mfma_f32_16x16x32_bf16(a, b, c, 0, 0, 0);
}

// ---------------- convert: x -> bf16, weights -> bf16 transposed -------------
__global__ void convert_k(const float* __restrict__ x, const float* __restrict__ Wq,
                          const float* __restrict__ Wkv, const float* __restrict__ Wg,
                          const float* __restrict__ Wo,
                          u16* __restrict__ xb, u16* __restrict__ WcatT, u16* __restrict__ WoT) {
  int i = blockIdx.x * 256 + threadIdx.x;
  if (i < 1048576) { xb[i] = f2bf(x[i]); return; }
  i -= 1048576;
  if (i < 524288) {
    int n = i >> 8, kk = i & 255;
    float v;
    if (n < 512) v = Wq[kk * 512 + n];
    else if (n < 1536) v = Wkv[kk * 1024 + (n - 512)];
    else v = Wg[kk * 512 + (n - 1536)];
    WcatT[i] = f2bf(v);
    return;
  }
  i -= 524288;
  if (i < 131072) {
    int n = i >> 9, kk = i & 511;
    WoT[i] = f2bf(Wo[kk * 256 + n]);
  }
}

// ---------------- GEMM1: [4096,256] x [256,2048] -> q,k,v,g ------------------
__global__ __launch_bounds__(256) void gemm_qkvg(
    const u16* __restrict__ xb, const u16* __restrict__ WcatT, const float* __restrict__ bg,
    u16* __restrict__ qb, u16* __restrict__ kb, u16* __restrict__ vb, u16* __restrict__ gb) {
  __shared__ __attribute__((aligned(16))) u16 As[128 * 40];
  __shared__ __attribute__((aligned(16))) u16 Bs[128 * 40];
  const int tid = threadIdx.x;
  const int wave = tid >> 6, lane = tid & 63;
  const int lane15 = lane & 15, quad = lane >> 4;
  const int rm0 = blockIdx.x * 128;
  const int cn0 = blockIdx.y * 128;
  const int wm = (wave & 1) * 64, wn = (wave >> 1) * 64;
  const int arow = tid >> 2;
  const int aseg = (tid & 3) * 8;
  floatx4 acc[4][4] = {};
#pragma unroll 1
  for (int k0 = 0; k0 < 256; k0 += 32) {
#pragma unroll
    for (int p = 0; p < 2; ++p) {
      int row = arow + p * 64;
      uint4 va = *(const uint4*)(xb + (rm0 + row) * 256 + k0 + aseg);
      *(uint4*)(As + row * 40 + aseg) = va;
      uint4 vbv = *(const uint4*)(WcatT + (cn0 + row) * 256 + k0 + aseg);
      *(uint4*)(Bs + row * 40 + aseg) = vbv;
    }
    __syncthreads();
    bf16x8 af[4], bfr[4];
#pragma unroll
    for (int mt = 0; mt < 4; ++mt) af[mt] = *(const bf16x8*)(As + (wm + mt * 16 + lane15) * 40 + quad * 8);
#pragma unroll
    for (int nt = 0; nt < 4; ++nt) bfr[nt] = *(const bf16x8*)(Bs + (wn + nt * 16 + lane15) * 40 + quad * 8);
#pragma unroll
    for (int mt = 0; mt < 4; ++mt)
#pragma unroll
      for (int nt = 0; nt < 4; ++nt)
        acc[mt][nt] = MFMA(af[mt], bfr[nt], acc[mt][nt]);
    __syncthreads();
  }
#pragma unroll
  for (int mt = 0; mt < 4; ++mt)
#pragma unroll
    for (int nt = 0; nt < 4; ++nt)
#pragma unroll
      for (int r = 0; r < 4; ++r) {
        int row = rm0 + wm + mt * 16 + quad * 4 + r;
        int col = cn0 + wn + nt * 16 + lane15;
        float v = acc[mt][nt][r];
        int b = row >> 10, n = row & 1023;
        if (col < 512) {
          int h = col >> 6, d = col & 63;
          qb[((b * 8 + h) * 1024 + n) * 64 + d] = f2bf(v * 0.125f);
        } else if (col < 1024) {
          int c = col - 512, h = c >> 6, d = c & 63;
          kb[((b * 8 + h) * 1024 + n) * 64 + d] = f2bf(v);
        } else if (col < 1536) {
          int c = col - 1024, h = c >> 6, d = c & 63;
          vb[((b * 8 + h) * 1024 + n) * 64 + d] = f2bf(v);
        } else {
          int c = col - 1536;
          float g = 1.0f / (1.0f + __expf(-(v + bg[c])));
          gb[row * 512 + c] = f2bf(g);
        }
      }
}

// ---------------- V transpose: vb[bh][n][d] -> vT[bh][d][n] ------------------
__global__ __launch_bounds__(256) void vtrans_k(const u16* __restrict__ vb, u16* __restrict__ vT) {
  __shared__ __attribute__((aligned(16))) u16 L[64 * 72];
  const int bh = blockIdx.x, n0 = blockIdx.y * 64;
  const int t = threadIdx.x;
  const int row = t >> 2, seg = t & 3;
  const uint4* src = (const uint4*)(vb + ((size_t)bh * 1024 + n0 + row) * 64 + seg * 16);
  *(uint4*)(L + row * 72 + seg * 16) = src[0];
  *(uint4*)(L + row * 72 + seg * 16 + 8) = src[1];
  __syncthreads();
  const int d = t >> 2, jb = (t & 3) * 16;
  u16 tmp[16];
#pragma unroll
  for (int e = 0; e < 16; ++e) tmp[e] = L[(jb + e) * 72 + d];
  uint4* dst = (uint4*)(vT + ((size_t)bh * 64 + d) * 1024 + n0 + jb);
  dst[0] = *(uint4*)(tmp);
  dst[1] = *(uint4*)(tmp + 8);
}

// ------------- attention: barrier-free flash, 64 Q-rows / block --------------
__global__ __launch_bounds__(256, 2) void attn_k(
    const u16* __restrict__ qb, const u16* __restrict__ kb, const u16* __restrict__ vT,
    const float* __restrict__ bias, const u16* __restrict__ gb, u16* __restrict__ outgb) {
  __shared__ __attribute__((aligned(16))) u16 Ps[4 * 16 * 136];
  const int tid = threadIdx.x;
  const int wave = tid >> 6, lane = tid & 63;
  const int lane15 = lane & 15, quad = lane >> 4;
  const int bh = blockIdx.x;
  const int q0 = blockIdx.y * 64;

  bf16x8 qf0, qf1;
  {
    const u16* qrow = qb + ((size_t)(bh * 1024 + q0 + wave * 16 + lane15)) * 64 + quad * 8;
    qf0 = *(const bf16x8*)(qrow);
    qf1 = *(const bf16x8*)(qrow + 32);
  }
  bf16x8 ones;
#pragma unroll
  for (int e = 0; e < 8; ++e) ones[e] = __builtin_bit_cast(__bf16, (u16)0x3F80);

  floatx4 oacc[4] = {};
  float m_run[4], l_run[4];
#pragma unroll
  for (int r = 0; r < 4; ++r) { m_run[r] = -1e38f; l_run[r] = 0.f; }

  u16* Pw = Ps + wave * (16 * 136);
  const u16* kp = kb + (size_t)bh * 65536;
  const u16* vp = vT + (size_t)bh * 65536;
  const float* bb = bias + ((size_t)(bh * 1024 + q0 + wave * 16 + quad * 4)) * 1024;

#pragma unroll 1
  for (int kt = 0; kt < 8; ++kt) {
    const int kb0 = kt * 128;
    // K fragments (direct global, B-layout) — all independent loads
    bf16x8 kf0[8], kf1[8];
#pragma unroll
    for (int nt = 0; nt < 8; ++nt) {
      const u16* kr = kp + ((size_t)(kb0 + nt * 16 + lane15)) * 64 + quad * 8;
      kf0[nt] = *(const bf16x8*)kr;
      kf1[nt] = *(const bf16x8*)(kr + 32);
    }
    // bias loads (C-layout direct; 16 lanes x 4B = full 64B lines)
    float bv[8][4];
#pragma unroll
    for (int nt = 0; nt < 8; ++nt)
#pragma unroll
      for (int r = 0; r < 4; ++r)
        bv[nt][r] = bb[(size_t)r * 1024 + kb0 + nt * 16 + lane15];
    // V^T fragments (direct global, B-layout) — prefetch for PV
    bf16x8 vf[4][4];
#pragma unroll
    for (int dt = 0; dt < 4; ++dt)
#pragma unroll
      for (int ck = 0; ck < 4; ++ck)
        vf[dt][ck] = *(const bf16x8*)(vp + ((size_t)(dt * 16 + lane15)) * 1024 + kb0 + ck * 32 + quad * 8);

    // S = Q K^T + bias
    floatx4 s[8];
#pragma unroll
    for (int nt = 0; nt < 8; ++nt) {
      floatx4 z = {};
      z = MFMA(qf0, kf0[nt], z);
      s[nt] = MFMA(qf1, kf1[nt], z);
#pragma unroll
      for (int r = 0; r < 4; ++r) s[nt][r] += bv[nt][r];
    }

    // online softmax: max via shuffle, sum via ones-MFMA
    float alpha[4];
#pragma unroll
    for (int r = 0; r < 4; ++r) {
      float mx = s[0][r];
#pragma unroll
      for (int nt = 1; nt < 8; ++nt) mx = fmaxf(mx, s[nt][r]);
#pragma unroll
      for (int off = 1; off < 16; off <<= 1) mx = fmaxf(mx, __shfl_xor(mx, off, 64));
      float m_new = fmaxf(m_run[r], mx);
      alpha[r] = __expf(m_run[r] - m_new);
      m_run[r] = m_new;
#pragma unroll
      for (int nt = 0; nt < 8; ++nt) s[nt][r] = __expf(s[nt][r] - m_new);
    }
    // P -> wave-private LDS (C-layout write, A-layout read; no barrier needed)
#pragma unroll
    for (int nt = 0; nt < 8; ++nt)
#pragma unroll
      for (int r = 0; r < 4; ++r)
        Pw[(quad * 4 + r) * 136 + nt * 16 + lane15] = f2bf(s[nt][r]);
    bf16x8 pf[4];
#pragma unroll
    for (int ck = 0; ck < 4; ++ck) pf[ck] = *(const bf16x8*)(Pw + lane15 * 136 + ck * 32 + quad * 8);

    // row-sum via MFMA against ones + rescale + PV
    floatx4 lacc = {};
#pragma unroll
    for (int ck = 0; ck < 4; ++ck) lacc = MFMA(pf[ck], ones, lacc);
#pragma unroll
    for (int r = 0; r < 4; ++r) {
      l_run[r] = l_run[r] * alpha[r] + lacc[r];
#pragma unroll
      for (int dt = 0; dt < 4; ++dt) oacc[dt][r] *= alpha[r];
    }
#pragma unroll
    for (int dt = 0; dt < 4; ++dt)
#pragma unroll
      for (int ck = 0; ck < 4; ++ck)
        oacc[dt] = MFMA(pf[ck], vf[dt][ck], oacc[dt]);
  }

  // epilogue: normalize, gate, store bf16 outg [4096][512]
  const int h = bh & 7, b = bh >> 3;
#pragma unroll
  for (int dt = 0; dt < 4; ++dt)
#pragma unroll
    for (int r = 0; r < 4; ++r) {
      int nrow = q0 + wave * 16 + quad * 4 + r;
      float v = oacc[dt][r] / l_run[r];
      int inner = h * 64 + dt * 16 + lane15;
      size_t idx = ((size_t)(b * 1024 + nrow)) * 512 + inner;
      float g = bf2f(gb[idx]);
      outgb[idx] = f2bf(v * g);
    }
}

// ---------------- GEMM2: [4096,512] x [512,256] + bo -> out fp32 -------------
__global__ __launch_bounds__(256) void gemm_out(
    const u16* __restrict__ og, const u16* __restrict__ WoT, const float* __restrict__ bo,
    float* __restrict__ out) {
  __shared__ __attribute__((aligned(16))) u16 As[128 * 40];
  __shared__ __attribute__((aligned(16))) u16 Bs[128 * 40];
  const int tid = threadIdx.x;
  const int wave = tid >> 6, lane = tid & 63;
  const int lane15 = lane & 15, quad = lane >> 4;
  const int rm0 = blockIdx.x * 128;
  const int cn0 = blockIdx.y * 128;
  const int wm = (wave & 1) * 64, wn = (wave >> 1) * 64;
  const int arow = tid >> 2;
  const int aseg = (tid & 3) * 8;
  floatx4 acc[4][4] = {};
#pragma unroll 1
  for (int k0 = 0; k0 < 512; k0 += 32) {
#pragma unroll
    for (int p = 0; p < 2; ++p) {
      int row = arow + p * 64;
      uint4 va = *(const uint4*)(og + (rm0 + row) * 512 + k0 + aseg);
      *(uint4*)(As + row * 40 + aseg) = va;
      uint4 vbv = *(const uint4*)(WoT + (cn0 + row) * 512 + k0 + aseg);
      *(uint4*)(Bs + row * 40 + aseg) = vbv;
    }
    __syncthreads();
    bf16x8 af[4], bfr[4];
#pragma unroll
    for (int mt = 0; mt < 4; ++mt) af[mt] = *(const bf16x8*)(As + (wm + mt * 16 + lane15) * 40 + quad * 8);
#pragma unroll
    for (int nt = 0; nt < 4; ++nt) bfr[nt] = *(const bf16x8*)(Bs + (wn + nt * 16 + lane15) * 40 + quad * 8);
#pragma unroll
    for (int mt = 0; mt < 4; ++mt)
#pragma unroll
      for (int nt = 0; nt < 4; ++nt)
        acc[mt][nt] = MFMA(af[mt], bfr[nt], acc[mt][nt]);
    __syncthreads();
  }
#pragma unroll
  for (int mt = 0; mt < 4; ++mt)
#pragma unroll
    for (int nt = 0; nt < 4; ++nt)
#pragma unroll
      for (int r = 0; r < 4; ++r) {
        int row = rm0 + wm + mt * 16 + quad * 4 + r;
        int col = cn0 + wn + nt * 16 + lane15;
        out[row * 256 + col] = acc[mt][nt][r] + bo[col];
      }
}

extern "C" void kernel_launch(void* const* d_in, const int* in_sizes, int n_in,
                              void* d_out, int out_size, void* d_ws, size_t ws_size,
                              hipStream_t stream) {
  const float* x = (const float*)d_in[0];
  const float* bias = (const float*)d_in[1];
  const float* Wq = (const float*)d_in[2];
  const float* Wkv = (const float*)d_in[3];
  const float* Wo = (const float*)d_in[4];
  const float* bo = (const float*)d_in[5];
  const float* Wg = (const float*)d_in[6];
  const float* bg = (const float*)d_in[7];
  float* out = (float*)d_out;
  char* ws = (char*)d_ws;
  u16* xb    = (u16*)(ws);                 // 2 MB
  u16* WcatT = (u16*)(ws + 2097152);       // 1 MB
  u16* WoT   = (u16*)(ws + 3145728);       // 256 KB
  u16* qb    = (u16*)(ws + 3407872);       // 4 MB
  u16* kb    = (u16*)(ws + 7602176);       // 4 MB
  u16* vb    = (u16*)(ws + 11796480);      // 4 MB
  u16* gb    = (u16*)(ws + 15990784);      // 4 MB
  u16* ogb   = (u16*)(ws + 20185088);      // 4 MB
  u16* vTb   = (u16*)(ws + 24379392);      // 4 MB

  convert_k<<<6656, 256, 0, stream>>>(x, Wq, Wkv, Wg, Wo, xb, WcatT, WoT);
  dim3 g1(32, 16);
  gemm_qkvg<<<g1, 256, 0, stream>>>(xb, WcatT, bg, qb, kb, vb, gb);
  dim3 gv(32, 16);
  vtrans_k<<<gv, 256, 0, stream>>>(vb, vTb);
  dim3 g2(32, 16);
  attn_k<<<g2, 256, 0, stream>>>(qb, kb, vTb, bias, gb, ogb);
  dim3 g3(32, 2);
  gemm_out<<<g3, 256, 0, stream>>>(ogb, WoT, bo, out);
}